// Round 4
// baseline (63.388 us; speedup 1.0000x reference)
//
#include <hip/hip_runtime.h>
#include <hip/hip_fp16.h>
#include <stdint.h>

// ---------------- problem constants ----------------
#define KR      4288        // 67 K-steps * 64: 128 main slices + 4 ext (wb3) + bW3 + zero
#define LN_EPS  1e-5f

typedef _Float16 f16;
typedef __attribute__((ext_vector_type(2))) _Float16 h2v;
typedef __attribute__((ext_vector_type(4))) _Float16 h4v;
typedef __attribute__((ext_vector_type(8))) _Float16 h8v;
typedef __attribute__((ext_vector_type(4))) float    f32x4;

union H2U { uint32_t u; h2v h; };
union H8U { uint32_t u[4]; h8v v; };

// ============================================================
// Kernel 1: pack W3-like operand to f16, row-major [o][KR], no swizzle.
// slices 0..127: wW3 ; 128..131: wb3 (A=x) ; 132: bW3 (A=h2b) ; 133: zeros.
// ============================================================
__global__ __launch_bounds__(256) void prep_w3(
    const float* __restrict__ wW3, const float* __restrict__ wb3,
    const float* __restrict__ bW3, f16* __restrict__ w3h)
{
  const int cid = blockIdx.x * 256 + threadIdx.x;   // 8-elem chunk in a row
  const int o   = blockIdx.y;
  if (cid >= KR / 8) return;
  const int k0    = cid * 8;
  const int slice = k0 >> 5;
  const int h0    = k0 & 31;
  float v[8];
  if (slice < 133) {
    const float* src;
    if      (slice < 128) src = wW3 + ((size_t)o * 128 + slice) * 32 + h0;
    else if (slice < 132) src = wb3 + (size_t)o * 128 + (slice - 128) * 32 + h0;
    else                  src = bW3 + (size_t)o * 32 + h0;
    float4 a = *(const float4*)src;
    float4 b = *(const float4*)(src + 4);
    v[0]=a.x; v[1]=a.y; v[2]=a.z; v[3]=a.w; v[4]=b.x; v[5]=b.y; v[6]=b.z; v[7]=b.w;
  } else {
#pragma unroll
    for (int j = 0; j < 8; ++j) v[j] = 0.f;
  }
  h8v pk;
#pragma unroll
  for (int j = 0; j < 8; ++j) pk[j] = (f16)v[j];
  *(h8v*)(w3h + (size_t)o * KR + k0) = pk;
}

// ============================================================
// Kernel 2 (fused): hyper-MLP prologue + barrier-free reg-pipelined U-GEMM.
// grid 512 = 256 token-tiles x splitK 2. Block 256 = 4 waves, each wave owns
// a 64x32 output tile (same 64 tokens, o-strip = wid*32). K halves: 34 + 33
// iters of K=64. No LDS for B: fragments loaded direct-to-register, depth-2
// pipelined, no barriers in the main loop. Output via fp32 atomicAdd
// (2-way commutative => bit-deterministic); half 1 adds bb3.
// ============================================================
__global__ __launch_bounds__(256) void fused_kernel(
    const float* __restrict__ x, const float* __restrict__ z,
    const float* __restrict__ wW1, const float* __restrict__ wb1,
    const float* __restrict__ wg1, const float* __restrict__ wbe1,
    const float* __restrict__ wW2, const float* __restrict__ wb2,
    const float* __restrict__ wg2, const float* __restrict__ wbe2,
    const float* __restrict__ bW1, const float* __restrict__ bb1,
    const float* __restrict__ bg1, const float* __restrict__ bbe1,
    const float* __restrict__ bW2, const float* __restrict__ bb2,
    const float* __restrict__ bg2, const float* __restrict__ bbe2,
    const float* __restrict__ bb3,
    const f16* __restrict__ w3h, float* __restrict__ out)
{
  __shared__ __align__(16) f16 xs[64][136];     // x tile f16 (17.4 KB)
  __shared__ __align__(16) f16 h2w_s[64][40];   // weight-branch h2 (5.1 KB)
  __shared__ __align__(16) f16 h2b_s[64][40];   // bias-branch h2 (5.1 KB)

  const int tid  = threadIdx.x;
  const int lane = tid & 63;
  const int wid  = tid >> 6;
  const int lm   = lane & 15, hc = lane >> 4, hbase = hc * 8;
  const int tile = blockIdx.x >> 1;
  const int kh   = blockIdx.x & 1;              // K-half
  const int t0   = tile * 64;
  const int o0   = wid * 32;
  const int ks0    = kh * 34;
  const int n_iter = kh ? 33 : 34;

  // bias values (added by half 1 only; uniform branch-free)
  float bbv[2];
#pragma unroll
  for (int n = 0; n < 2; ++n) bbv[n] = bb3[o0 + n * 16 + lm] * (float)kh;

  // ---- stage x tile: fp32 global -> f16 LDS ----
  {
    const int r = tid >> 2, q = tid & 3;
    const float* src = x + (size_t)(t0 + r) * 128 + q * 32;
#pragma unroll
    for (int u = 0; u < 8; ++u) {
      float4 v = *(const float4*)(src + u * 4);
      h4v p; p[0] = (f16)v.x; p[1] = (f16)v.y; p[2] = (f16)v.z; p[3] = (f16)v.w;
      *(h4v*)&xs[r][q * 32 + u * 4] = p;
    }
  }

  // ---- hyper MLP: threads 0..127, one eval each, no cross-lane ops ----
  if (tid < 128) {
    const int br  = tid >> 6;          // 0 = weight branch, 1 = bias branch
    const int row = tid & 63;
    const int tok = t0 + row;
    const float* W1  = br ? bW1  : wW1;  const float* b1  = br ? bb1  : wb1;
    const float* g1  = br ? bg1  : wg1;  const float* be1 = br ? bbe1 : wbe1;
    const float* W2  = br ? bW2  : wW2;  const float* b2  = br ? bb2  : wb2;
    const float* g2  = br ? bg2  : wg2;  const float* be2 = br ? bbe2 : wbe2;

    const float z0 = z[tok * 3 + 0], z1 = z[tok * 3 + 1], z2 = z[tok * 3 + 2];

    float h1[32];
    float s = 0.f, s2 = 0.f;
#pragma unroll
    for (int j = 0; j < 32; ++j) {
      float v = W1[j * 3] * z0 + W1[j * 3 + 1] * z1 + W1[j * 3 + 2] * z2 + b1[j];
      h1[j] = v; s += v; s2 += v * v;
    }
    float mu  = s * (1.f / 32.f);
    float var = fmaxf(s2 * (1.f / 32.f) - mu * mu, 0.f);
    float rr  = rsqrtf(var + LN_EPS);
#pragma unroll
    for (int j = 0; j < 32; ++j)
      h1[j] = fmaxf((h1[j] - mu) * rr * g1[j] + be1[j], 0.f);

    float h2a[32];
    s = 0.f; s2 = 0.f;
#pragma unroll
    for (int j = 0; j < 32; ++j) {
      float acc = b2[j];
#pragma unroll
      for (int kk = 0; kk < 8; ++kk) {
        float4 w = *(const float4*)&W2[j * 32 + kk * 4];
        acc += w.x * h1[kk * 4] + w.y * h1[kk * 4 + 1]
             + w.z * h1[kk * 4 + 2] + w.w * h1[kk * 4 + 3];
      }
      h2a[j] = acc; s += acc; s2 += acc * acc;
    }
    mu  = s * (1.f / 32.f);
    var = fmaxf(s2 * (1.f / 32.f) - mu * mu, 0.f);
    rr  = rsqrtf(var + LN_EPS);
    f16* dst = br ? &h2b_s[row][0] : &h2w_s[row][0];
#pragma unroll
    for (int j4 = 0; j4 < 8; ++j4) {
      h4v w;
      w[0] = (f16)fmaxf((h2a[j4*4+0] - mu) * rr * g2[j4*4+0] + be2[j4*4+0], 0.f);
      w[1] = (f16)fmaxf((h2a[j4*4+1] - mu) * rr * g2[j4*4+1] + be2[j4*4+1], 0.f);
      w[2] = (f16)fmaxf((h2a[j4*4+2] - mu) * rr * g2[j4*4+2] + be2[j4*4+2], 0.f);
      w[3] = (f16)fmaxf((h2a[j4*4+3] - mu) * rr * g2[j4*4+3] + be2[j4*4+3], 0.f);
      *(h4v*)&dst[j4 * 4] = w;
    }
  }

  __syncthreads();   // the only barrier in the kernel

  // ---- per-lane h2 fragment (packed f16 pairs), rows m*16+lm ----
  uint32_t h2p[4][4];
#pragma unroll
  for (int m = 0; m < 4; ++m) {
    H8U c; c.v = *(const h8v*)&h2w_s[m * 16 + lm][hbase];
#pragma unroll
    for (int q = 0; q < 4; ++q) h2p[m][q] = c.u[q];
  }

  // ---- B-fragment pointers [i2][n], advance 64 f16 (128B) per iter ----
  const f16* bp00 = w3h + (size_t)(o0 + lm)      * KR + (ks0 * 2    ) * 32 + hbase;
  const f16* bp01 = w3h + (size_t)(o0 + 16 + lm) * KR + (ks0 * 2    ) * 32 + hbase;
  const f16* bp10 = w3h + (size_t)(o0 + lm)      * KR + (ks0 * 2 + 1) * 32 + hbase;
  const f16* bp11 = w3h + (size_t)(o0 + 16 + lm) * KR + (ks0 * 2 + 1) * 32 + hbase;

#define LOADSET(S) do { \
    S[0][0] = *(const h8v*)bp00; bp00 += 64; \
    S[0][1] = *(const h8v*)bp01; bp01 += 64; \
    S[1][0] = *(const h8v*)bp10; bp10 += 64; \
    S[1][1] = *(const h8v*)bp11; bp11 += 64; } while (0)

  f32x4 acc[4][2];
#pragma unroll
  for (int m = 0; m < 4; ++m)
#pragma unroll
    for (int n = 0; n < 2; ++n) acc[m][n] = (f32x4){0.f, 0.f, 0.f, 0.f};

  auto STEP = [&](h8v (&bs)[2][2], int ks) {
    const int ksg = ks0 + ks;
    h8v af0[4], af1[4];
    if (ksg < 64) {
      // main slices: A = x (f16) * h2 (f16), 8 pk_mul per row
#pragma unroll
      for (int m = 0; m < 4; ++m) {
        const uint32_t xp = *(const uint32_t*)&xs[m * 16 + lm][2 * ksg];
        H2U x0, x1;
        x0.u = (xp & 0xffffu) | (xp << 16);
        x1.u = (xp >> 16) | (xp & 0xffff0000u);
        H8U r0, r1;
#pragma unroll
        for (int q = 0; q < 4; ++q) {
          H2U hq; hq.u = h2p[m][q];
          H2U p0; p0.h = x0.h * hq.h; r0.u[q] = p0.u;
          H2U p1; p1.h = x1.h * hq.h; r1.u[q] = p1.u;
        }
        af0[m] = r0.v; af1[m] = r1.v;
      }
    } else if (ksg < 66) {
      // ext slices (b3 term): A = x directly
      const int s = (ksg - 64) * 2;
#pragma unroll
      for (int m = 0; m < 4; ++m) {
        af0[m] = *(const h8v*)&xs[m * 16 + lm][s * 32 + hbase];
        af1[m] = *(const h8v*)&xs[m * 16 + lm][(s + 1) * 32 + hbase];
      }
    } else {
      // bias slice (A = h2b); i2=1 pairs with zero B
#pragma unroll
      for (int m = 0; m < 4; ++m) {
        af0[m] = *(const h8v*)&h2b_s[m * 16 + lm][hbase];
        af1[m] = af0[m];
      }
    }
#pragma unroll
    for (int n = 0; n < 2; ++n)
#pragma unroll
      for (int m = 0; m < 4; ++m)
        acc[m][n] = __builtin_amdgcn_mfma_f32_16x16x32_f16(af0[m], bs[0][n], acc[m][n], 0, 0, 0);
#pragma unroll
    for (int n = 0; n < 2; ++n)
#pragma unroll
      for (int m = 0; m < 4; ++m)
        acc[m][n] = __builtin_amdgcn_mfma_f32_16x16x32_f16(af1[m], bs[1][n], acc[m][n], 0, 0, 0);
  };

  h8v bA[2][2], bB[2][2];
  LOADSET(bA);            // ks = 0
  LOADSET(bB);            // ks = 1

  int ks = 0;
#pragma unroll 1
  while (ks + 2 <= n_iter) {
    STEP(bA, ks);
    if (ks + 2 < n_iter) LOADSET(bA);
    STEP(bB, ks + 1);
    if (ks + 3 < n_iter) LOADSET(bB);
    ks += 2;
  }
  if (ks < n_iter) STEP(bA, ks);

  // ---- epilogue: C/D layout col=lane&15, row=(lane>>4)*4+reg; atomic sum ----
#pragma unroll
  for (int m = 0; m < 4; ++m) {
#pragma unroll
    for (int n = 0; n < 2; ++n) {
      const int gc = o0 + n * 16 + lm;
#pragma unroll
      for (int r_ = 0; r_ < 4; ++r_) {
        const int row = t0 + m * 16 + hc * 4 + r_;
        atomicAdd(&out[(size_t)row * 128 + gc], acc[m][n][r_] + bbv[n]);
      }
    }
  }
#undef LOADSET
}

// ============================================================
extern "C" void kernel_launch(void* const* d_in, const int* in_sizes, int n_in,
                              void* d_out, int out_size, void* d_ws, size_t ws_size,
                              hipStream_t stream)
{
  const float* x    = (const float*)d_in[0];
  const float* z    = (const float*)d_in[1];
  const float* wW1  = (const float*)d_in[2];
  const float* wb1  = (const float*)d_in[3];
  const float* wg1  = (const float*)d_in[4];
  const float* wbe1 = (const float*)d_in[5];
  const float* wW2  = (const float*)d_in[6];
  const float* wb2  = (const float*)d_in[7];
  const float* wg2  = (const float*)d_in[8];
  const float* wbe2 = (const float*)d_in[9];
  const float* wW3  = (const float*)d_in[10];
  const float* wb3  = (const float*)d_in[11];
  const float* bW1  = (const float*)d_in[12];
  const float* bb1  = (const float*)d_in[13];
  const float* bg1  = (const float*)d_in[14];
  const float* bbe1 = (const float*)d_in[15];
  const float* bW2  = (const float*)d_in[16];
  const float* bb2  = (const float*)d_in[17];
  const float* bg2  = (const float*)d_in[18];
  const float* bbe2 = (const float*)d_in[19];
  const float* bW3  = (const float*)d_in[20];
  const float* bb3  = (const float*)d_in[21];

  f16*   w3h  = (f16*)d_ws;                 // 128*4288*2 = 1,097,728 B
  float* outf = (float*)d_out;

  hipMemsetAsync(d_out, 0, (size_t)16384 * 128 * sizeof(float), stream);
  hipLaunchKernelGGL(prep_w3, dim3(3, 128), dim3(256), 0, stream,
                     wW3, wb3, bW3, w3h);
  hipLaunchKernelGGL(fused_kernel, dim3(512), dim3(256), 0, stream,
                     x, z,
                     wW1, wb1, wg1, wbe1, wW2, wb2, wg2, wbe2,
                     bW1, bb1, bg1, bbe1, bW2, bb2, bg2, bbe2,
                     bb3, w3h, outf);
}